// Round 2
// baseline (715.184 us; speedup 1.0000x reference)
//
#include <hip/hip_runtime.h>
#include <stdint.h>

typedef __attribute__((ext_vector_type(8))) short bf16x8;
typedef __attribute__((ext_vector_type(4))) float f32x4;

typedef __attribute__((address_space(3))) uint32_t lds_u32_t;
typedef __attribute__((address_space(1))) const uint32_t glb_u32_t;

static __device__ __forceinline__ ushort f2bf(float f) {
  uint32_t u = __float_as_uint(f);
  uint32_t r = (u + 0x7FFFu + ((u >> 16) & 1u)) >> 16;
  return (ushort)r;
}
static __device__ __forceinline__ float bf2f(ushort u) {
  return __uint_as_float(((uint32_t)u) << 16);
}

// ---------------- cast fp32 -> bf16 (vectorized) ----------------
__global__ __launch_bounds__(256) void cast_f32_to_bf16(const float* __restrict__ src,
                                                        ushort* __restrict__ dst, int n4) {
  int stride = gridDim.x * blockDim.x;
  for (int i = blockIdx.x * blockDim.x + threadIdx.x; i < n4; i += stride) {
    float4 v = ((const float4*)src)[i];
    ushort4 o;
    o.x = f2bf(v.x); o.y = f2bf(v.y); o.z = f2bf(v.z); o.w = f2bf(v.w);
    ((ushort4*)dst)[i] = o;
  }
}

// ---------------- RoPE cos/sin table: [T=2048][64] ----------------
__global__ __launch_bounds__(256) void rope_table_kernel(float* __restrict__ cs,
                                                         float* __restrict__ sn) {
  int idx = blockIdx.x * blockDim.x + threadIdx.x;  // 2048*64
  int t = idx >> 6, j = idx & 63;
  float inv_freq = expf(-(2.0f * (float)j / 128.0f) * 9.210340371976184f);
  float ang = (float)t * inv_freq;
  cs[idx] = cosf(ang);
  sn[idx] = sinf(ang);
}

// ---------------- RMSNorm row kernel: fp32 in -> bf16 out ----------------
__global__ __launch_bounds__(256) void rmsnorm_kernel(const float* __restrict__ x,
                                                      const float* __restrict__ w,
                                                      ushort* __restrict__ out) {
  const int C = 2048;
  int row = blockIdx.x;
  int tid = threadIdx.x;
  int lane = tid & 63, wid = tid >> 6;
  const float* xr = x + (size_t)row * C;
  float4 a = ((const float4*)xr)[tid * 2];
  float4 b = ((const float4*)xr)[tid * 2 + 1];
  float ss = a.x * a.x + a.y * a.y + a.z * a.z + a.w * a.w +
             b.x * b.x + b.y * b.y + b.z * b.z + b.w * b.w;
#pragma unroll
  for (int off = 1; off < 64; off <<= 1) ss += __shfl_xor(ss, off);
  __shared__ float part[4];
  if (lane == 0) part[wid] = ss;
  __syncthreads();
  float tot = part[0] + part[1] + part[2] + part[3];
  float inv = rsqrtf(tot * (1.0f / 2048.0f) + 1e-5f);
  float4 wa = ((const float4*)w)[tid * 2];
  float4 wb = ((const float4*)w)[tid * 2 + 1];
  ushort* dst = out + (size_t)row * C + tid * 8;
  ushort4 o0, o1;
  o0.x = f2bf(a.x * inv * wa.x); o0.y = f2bf(a.y * inv * wa.y);
  o0.z = f2bf(a.z * inv * wa.z); o0.w = f2bf(a.w * inv * wa.w);
  o1.x = f2bf(b.x * inv * wb.x); o1.y = f2bf(b.y * inv * wb.y);
  o1.z = f2bf(b.z * inv * wb.z); o1.w = f2bf(b.w * inv * wb.w);
  ((ushort4*)dst)[0] = o0;
  ((ushort4*)dst)[1] = o1;
}

// ---------------- QKV GEMM: [4096,2048] x [6144,2048]^T + bias ----------------
// q,k -> [B,H,T,D] bf16 ; v -> TRANSPOSED [B,H,D,T] bf16
__global__ __launch_bounds__(256) void gemm_qkv_kernel(const ushort* __restrict__ A,
                                                       const ushort* __restrict__ W,
                                                       const float* __restrict__ bias,
                                                       ushort* __restrict__ qb,
                                                       ushort* __restrict__ kb,
                                                       ushort* __restrict__ vb) {
  const int K = 2048;
  __shared__ ushort lA[128 * 32];
  __shared__ ushort lB[128 * 32];
  const int tid = threadIdx.x;
  const int lane = tid & 63, wid = tid >> 6;
  const int wr = wid >> 1, wc = wid & 1;
  const int ar = lane & 15, ak = (lane >> 4) * 8;
  const int row0 = blockIdx.y * 128;
  const int col0 = blockIdx.x * 128;
  f32x4 acc[4][4];
#pragma unroll
  for (int m = 0; m < 4; ++m)
#pragma unroll
    for (int n = 0; n < 4; ++n) acc[m][n] = (f32x4){0.f, 0.f, 0.f, 0.f};
  for (int k0 = 0; k0 < K; k0 += 32) {
#pragma unroll
    for (int i = 0; i < 2; ++i) {
      int e = (i * 256 + tid) * 8;
      int r = e >> 5, c = e & 31;
      __builtin_amdgcn_global_load_lds((glb_u32_t*)(A + (size_t)(row0 + r) * K + k0 + c),
                                       (lds_u32_t*)(&lA[e]), 16, 0, 0);
      __builtin_amdgcn_global_load_lds((glb_u32_t*)(W + (size_t)(col0 + r) * K + k0 + c),
                                       (lds_u32_t*)(&lB[e]), 16, 0, 0);
    }
    __syncthreads();
    bf16x8 af[4], bfr[4];
#pragma unroll
    for (int m = 0; m < 4; ++m) af[m] = *(const bf16x8*)&lA[(wr * 64 + m * 16 + ar) * 32 + ak];
#pragma unroll
    for (int n = 0; n < 4; ++n) bfr[n] = *(const bf16x8*)&lB[(wc * 64 + n * 16 + ar) * 32 + ak];
#pragma unroll
    for (int m = 0; m < 4; ++m)
#pragma unroll
      for (int n = 0; n < 4; ++n)
        acc[m][n] = __builtin_amdgcn_mfma_f32_16x16x32_bf16(af[m], bfr[n], acc[m][n], 0, 0, 0);
    __syncthreads();
  }
  int s = col0 >> 11;
  int hh = (col0 >> 7) & 15;
  if (s < 2) {
    ushort* dst = (s == 0) ? qb : kb;
#pragma unroll
    for (int n = 0; n < 4; ++n) {
      int d = wc * 64 + n * 16 + ar;
      float bv = bias[col0 + d];
#pragma unroll
      for (int m = 0; m < 4; ++m) {
#pragma unroll
        for (int r = 0; r < 4; ++r) {
          int mrow = row0 + wr * 64 + m * 16 + (lane >> 4) * 4 + r;
          int bb = mrow >> 11, tt = mrow & 2047;
          dst[((size_t)(bb * 16 + hh) * 2048 + tt) * 128 + d] = f2bf(acc[m][n][r] + bv);
        }
      }
    }
  } else {
    // v transposed: vb[((b*16+h)*128 + d)*2048 + t]
#pragma unroll
    for (int n = 0; n < 4; ++n) {
      int d = wc * 64 + n * 16 + ar;
      float bv = bias[col0 + d];
#pragma unroll
      for (int m = 0; m < 4; ++m) {
        int t0 = row0 + wr * 64 + m * 16 + (lane >> 4) * 4;
        int bb = t0 >> 11, tt0 = t0 & 2047;
        ushort4 o;
        o.x = f2bf(acc[m][n][0] + bv);
        o.y = f2bf(acc[m][n][1] + bv);
        o.z = f2bf(acc[m][n][2] + bv);
        o.w = f2bf(acc[m][n][3] + bv);
        *(ushort4*)&vb[(((size_t)(bb * 16 + hh) * 128) + d) * 2048 + tt0] = o;
      }
    }
  }
}

// ---------------- RoPE in-place on q and k; fold 1/sqrt(D) into q ----------------
__global__ __launch_bounds__(256) void rope_apply_kernel(ushort* __restrict__ q,
                                                         ushort* __restrict__ k,
                                                         const float* __restrict__ cs,
                                                         const float* __restrict__ sn) {
  const float scale = 0.08838834764831845f;  // 1/sqrt(128)
  int row = blockIdx.x * 4 + (threadIdx.x >> 6);  // [B*H*T) rows
  int j = threadIdx.x & 63;
  int t = row & 2047;
  float c = cs[t * 64 + j], s = sn[t * 64 + j];
  size_t base = (size_t)row * 128;
  {
    float a = bf2f(q[base + j]), b = bf2f(q[base + 64 + j]);
    q[base + j] = f2bf((a * c - b * s) * scale);
    q[base + 64 + j] = f2bf((b * c + a * s) * scale);
  }
  {
    float a = bf2f(k[base + j]), b = bf2f(k[base + 64 + j]);
    k[base + j] = f2bf(a * c - b * s);
    k[base + 64 + j] = f2bf(b * c + a * s);
  }
}

// ---------------- causal flash attention (KVBLK=64, V pre-transposed) ----------------
// grid: (32, B*H); 4 waves/block; wave owns 16 q rows; qt reversed for balance
__global__ __launch_bounds__(256) void attn_kernel(const ushort* __restrict__ Q,
                                                   const ushort* __restrict__ K,
                                                   const ushort* __restrict__ Vt,
                                                   ushort* __restrict__ O) {
  __shared__ ushort plds[4][16][72];  // pad to 144B rows: 2-way bank alias (free)
  int bh = blockIdx.y;
  int b = bh >> 4, h = bh & 15;
  int lane = threadIdx.x & 63, wid = threadIdx.x >> 6;
  int ar = lane & 15, akk = (lane >> 4) * 8;
  const ushort* Qb = Q + (size_t)bh * (2048 * 128);
  const ushort* Kb = K + (size_t)bh * (2048 * 128);
  const ushort* Vtb = Vt + (size_t)bh * (128 * 2048);
  int qt = 31 - blockIdx.x;  // long blocks first
  int qrow0 = qt * 64 + wid * 16;
  bf16x8 qf[4];
#pragma unroll
  for (int kk = 0; kk < 4; ++kk)
    qf[kk] = *(const bf16x8*)&Qb[(size_t)(qrow0 + ar) * 128 + kk * 32 + akk];
  float m_r[4] = {-1e30f, -1e30f, -1e30f, -1e30f};
  float l_r[4] = {0.f, 0.f, 0.f, 0.f};
  f32x4 accO[8];
#pragma unroll
  for (int n = 0; n < 8; ++n) accO[n] = (f32x4){0.f, 0.f, 0.f, 0.f};
  int ntiles = qt + 1;
  for (int tt = 0; tt < ntiles; ++tt) {
    int kv0 = tt * 64;
    f32x4 s4[4];
#pragma unroll
    for (int n = 0; n < 4; ++n) {
      s4[n] = (f32x4){0.f, 0.f, 0.f, 0.f};
#pragma unroll
      for (int kk = 0; kk < 4; ++kk) {
        bf16x8 kf = *(const bf16x8*)&Kb[(size_t)(kv0 + n * 16 + ar) * 128 + kk * 32 + akk];
        s4[n] = __builtin_amdgcn_mfma_f32_16x16x32_bf16(qf[kk], kf, s4[n], 0, 0, 0);
      }
    }
    const bool masked = (tt == ntiles - 1);
    float corr[4];
#pragma unroll
    for (int r = 0; r < 4; ++r) {
      int row = qrow0 + (lane >> 4) * 4 + r;
      float v[4];
#pragma unroll
      for (int n = 0; n < 4; ++n) {
        int c = kv0 + n * 16 + ar;
        v[n] = (masked && c > row) ? -1e30f : s4[n][r];
      }
      float mx = fmaxf(fmaxf(v[0], v[1]), fmaxf(v[2], v[3]));
#pragma unroll
      for (int off = 1; off < 16; off <<= 1) mx = fmaxf(mx, __shfl_xor(mx, off));
      float mn = fmaxf(m_r[r], mx);
      float p0 = __expf(v[0] - mn), p1 = __expf(v[1] - mn);
      float p2 = __expf(v[2] - mn), p3 = __expf(v[3] - mn);
      float rs = (p0 + p1) + (p2 + p3);
#pragma unroll
      for (int off = 1; off < 16; off <<= 1) rs += __shfl_xor(rs, off);
      corr[r] = __expf(m_r[r] - mn);
      l_r[r] = l_r[r] * corr[r] + rs;
      m_r[r] = mn;
      int qr = (lane >> 4) * 4 + r;
      plds[wid][qr][ar] = f2bf(p0);
      plds[wid][qr][16 + ar] = f2bf(p1);
      plds[wid][qr][32 + ar] = f2bf(p2);
      plds[wid][qr][48 + ar] = f2bf(p3);
    }
#pragma unroll
    for (int n = 0; n < 8; ++n) {
#pragma unroll
      for (int r = 0; r < 4; ++r) accO[n][r] *= corr[r];
    }
    asm volatile("s_waitcnt lgkmcnt(0)" ::: "memory");
    bf16x8 pf0 = *(const bf16x8*)&plds[wid][ar][akk];
    bf16x8 pf1 = *(const bf16x8*)&plds[wid][ar][32 + akk];
#pragma unroll
    for (int n = 0; n < 8; ++n) {
      bf16x8 vf0 = *(const bf16x8*)&Vtb[(size_t)(n * 16 + ar) * 2048 + kv0 + akk];
      accO[n] = __builtin_amdgcn_mfma_f32_16x16x32_bf16(pf0, vf0, accO[n], 0, 0, 0);
      bf16x8 vf1 = *(const bf16x8*)&Vtb[(size_t)(n * 16 + ar) * 2048 + kv0 + 32 + akk];
      accO[n] = __builtin_amdgcn_mfma_f32_16x16x32_bf16(pf1, vf1, accO[n], 0, 0, 0);
    }
  }
  // write O to [B,T,H*D] (bf16) for the O-proj GEMM
#pragma unroll
  for (int r = 0; r < 4; ++r) {
    int trow = qrow0 + (lane >> 4) * 4 + r;
    float invl = 1.0f / l_r[r];
    ushort* orow = O + ((size_t)b * 2048 + trow) * 2048 + h * 128;
#pragma unroll
    for (int n = 0; n < 8; ++n) orow[n * 16 + ar] = f2bf(accO[n][r] * invl);
  }
}

// ---------------- O-proj GEMM: [4096,2048] x [2048,2048]^T + bias -> fp32 out ----------------
__global__ __launch_bounds__(256) void gemm_oproj_kernel(const ushort* __restrict__ A,
                                                         const ushort* __restrict__ W,
                                                         const float* __restrict__ bias,
                                                         float* __restrict__ out) {
  const int K = 2048;
  __shared__ ushort lA[128 * 32];
  __shared__ ushort lB[128 * 32];
  const int tid = threadIdx.x;
  const int lane = tid & 63, wid = tid >> 6;
  const int wr = wid >> 1, wc = wid & 1;
  const int ar = lane & 15, ak = (lane >> 4) * 8;
  const int row0 = blockIdx.y * 128;
  const int col0 = blockIdx.x * 128;
  f32x4 acc[4][4];
#pragma unroll
  for (int m = 0; m < 4; ++m)
#pragma unroll
    for (int n = 0; n < 4; ++n) acc[m][n] = (f32x4){0.f, 0.f, 0.f, 0.f};
  for (int k0 = 0; k0 < K; k0 += 32) {
#pragma unroll
    for (int i = 0; i < 2; ++i) {
      int e = (i * 256 + tid) * 8;
      int r = e >> 5, c = e & 31;
      __builtin_amdgcn_global_load_lds((glb_u32_t*)(A + (size_t)(row0 + r) * K + k0 + c),
                                       (lds_u32_t*)(&lA[e]), 16, 0, 0);
      __builtin_amdgcn_global_load_lds((glb_u32_t*)(W + (size_t)(col0 + r) * K + k0 + c),
                                       (lds_u32_t*)(&lB[e]), 16, 0, 0);
    }
    __syncthreads();
    bf16x8 af[4], bfr[4];
#pragma unroll
    for (int m = 0; m < 4; ++m) af[m] = *(const bf16x8*)&lA[(wr * 64 + m * 16 + ar) * 32 + ak];
#pragma unroll
    for (int n = 0; n < 4; ++n) bfr[n] = *(const bf16x8*)&lB[(wc * 64 + n * 16 + ar) * 32 + ak];
#pragma unroll
    for (int m = 0; m < 4; ++m)
#pragma unroll
      for (int n = 0; n < 4; ++n)
        acc[m][n] = __builtin_amdgcn_mfma_f32_16x16x32_bf16(af[m], bfr[n], acc[m][n], 0, 0, 0);
    __syncthreads();
  }
#pragma unroll
  for (int n = 0; n < 4; ++n) {
    int col = col0 + wc * 64 + n * 16 + ar;
    float bv = bias[col];
#pragma unroll
    for (int m = 0; m < 4; ++m) {
#pragma unroll
      for (int r = 0; r < 4; ++r) {
        int mrow = row0 + wr * 64 + m * 16 + (lane >> 4) * 4 + r;
        out[(size_t)mrow * 2048 + col] = acc[m][n][r] + bv;
      }
    }
  }
}

extern "C" void kernel_launch(void* const* d_in, const int* in_sizes, int n_in,
                              void* d_out, int out_size, void* d_ws, size_t ws_size,
                              hipStream_t stream) {
  const float* x = (const float*)d_in[0];
  const float* rmsw = (const float*)d_in[1];
  const float* qkv_w = (const float*)d_in[2];
  const float* qkv_b = (const float*)d_in[3];
  const float* o_w = (const float*)d_in[4];
  const float* o_b = (const float*)d_in[5];
  float* out = (float*)d_out;

  char* ws = (char*)d_ws;
  size_t off = 0;
  auto alloc = [&](size_t bytes) {
    void* p = ws + off;
    off += (bytes + 255) & ~(size_t)255;
    return p;
  };
  ushort* xn = (ushort*)alloc((size_t)4096 * 2048 * 2);  // later reused as attn_out
  ushort* wq = (ushort*)alloc((size_t)6144 * 2048 * 2);
  ushort* wo = (ushort*)alloc((size_t)2048 * 2048 * 2);
  ushort* qb = (ushort*)alloc((size_t)32 * 2048 * 128 * 2);
  ushort* kb = (ushort*)alloc((size_t)32 * 2048 * 128 * 2);
  ushort* vb = (ushort*)alloc((size_t)32 * 2048 * 128 * 2);  // [B,H,D,T]
  float* cs = (float*)alloc((size_t)2048 * 64 * 4);
  float* sn = (float*)alloc((size_t)2048 * 64 * 4);

  cast_f32_to_bf16<<<1024, 256, 0, stream>>>(qkv_w, wq, 6144 * 2048 / 4);
  cast_f32_to_bf16<<<1024, 256, 0, stream>>>(o_w, wo, 2048 * 2048 / 4);
  rope_table_kernel<<<512, 256, 0, stream>>>(cs, sn);
  rmsnorm_kernel<<<4096, 256, 0, stream>>>(x, rmsw, xn);
  gemm_qkv_kernel<<<dim3(48, 32), 256, 0, stream>>>(xn, wq, qkv_b, qb, kb, vb);
  rope_apply_kernel<<<16384, 256, 0, stream>>>(qb, kb, cs, sn);
  attn_kernel<<<dim3(32, 32), 256, 0, stream>>>(qb, kb, vb, xn /* attn_out */);
  gemm_oproj_kernel<<<dim3(16, 32), 256, 0, stream>>>(xn, wo, o_b, out);
}

// Round 3
// 345.053 us; speedup vs baseline: 2.0727x; 2.0727x over previous
//
#include <hip/hip_runtime.h>
#include <stdint.h>

typedef __attribute__((ext_vector_type(8))) short bf16x8;
typedef __attribute__((ext_vector_type(4))) float f32x4;

typedef __attribute__((address_space(3))) uint32_t lds_u32_t;
typedef __attribute__((address_space(1))) const uint32_t glb_u32_t;

static __device__ __forceinline__ ushort f2bf(float f) {
  uint32_t u = __float_as_uint(f);
  uint32_t r = (u + 0x7FFFu + ((u >> 16) & 1u)) >> 16;
  return (ushort)r;
}
static __device__ __forceinline__ float bf2f(ushort u) {
  return __uint_as_float(((uint32_t)u) << 16);
}

// ---------------- cast fp32 -> bf16 (vectorized) ----------------
__global__ __launch_bounds__(256) void cast_f32_to_bf16(const float* __restrict__ src,
                                                        ushort* __restrict__ dst, int n4) {
  int stride = gridDim.x * blockDim.x;
  for (int i = blockIdx.x * blockDim.x + threadIdx.x; i < n4; i += stride) {
    float4 v = ((const float4*)src)[i];
    ushort4 o;
    o.x = f2bf(v.x); o.y = f2bf(v.y); o.z = f2bf(v.z); o.w = f2bf(v.w);
    ((ushort4*)dst)[i] = o;
  }
}

// ---------------- RoPE cos/sin table: [T=2048][64] ----------------
__global__ __launch_bounds__(256) void rope_table_kernel(float* __restrict__ cs,
                                                         float* __restrict__ sn) {
  int idx = blockIdx.x * blockDim.x + threadIdx.x;  // 2048*64
  int t = idx >> 6, j = idx & 63;
  float inv_freq = expf(-(2.0f * (float)j / 128.0f) * 9.210340371976184f);
  float ang = (float)t * inv_freq;
  cs[idx] = cosf(ang);
  sn[idx] = sinf(ang);
}

// ---------------- RMSNorm row kernel: fp32 in -> bf16 out ----------------
__global__ __launch_bounds__(256) void rmsnorm_kernel(const float* __restrict__ x,
                                                      const float* __restrict__ w,
                                                      ushort* __restrict__ out) {
  const int C = 2048;
  int row = blockIdx.x;
  int tid = threadIdx.x;
  int lane = tid & 63, wid = tid >> 6;
  const float* xr = x + (size_t)row * C;
  float4 a = ((const float4*)xr)[tid * 2];
  float4 b = ((const float4*)xr)[tid * 2 + 1];
  float ss = a.x * a.x + a.y * a.y + a.z * a.z + a.w * a.w +
             b.x * b.x + b.y * b.y + b.z * b.z + b.w * b.w;
#pragma unroll
  for (int off = 1; off < 64; off <<= 1) ss += __shfl_xor(ss, off);
  __shared__ float part[4];
  if (lane == 0) part[wid] = ss;
  __syncthreads();
  float tot = part[0] + part[1] + part[2] + part[3];
  float inv = rsqrtf(tot * (1.0f / 2048.0f) + 1e-5f);
  float4 wa = ((const float4*)w)[tid * 2];
  float4 wb = ((const float4*)w)[tid * 2 + 1];
  ushort* dst = out + (size_t)row * C + tid * 8;
  ushort4 o0, o1;
  o0.x = f2bf(a.x * inv * wa.x); o0.y = f2bf(a.y * inv * wa.y);
  o0.z = f2bf(a.z * inv * wa.z); o0.w = f2bf(a.w * inv * wa.w);
  o1.x = f2bf(b.x * inv * wb.x); o1.y = f2bf(b.y * inv * wb.y);
  o1.z = f2bf(b.z * inv * wb.z); o1.w = f2bf(b.w * inv * wb.w);
  ((ushort4*)dst)[0] = o0;
  ((ushort4*)dst)[1] = o1;
}

// ---------------- QKV GEMM: [4096,2048] x [6144,2048]^T + bias ----------------
// q,k -> [B,H,T,D] bf16 ; v -> TRANSPOSED [B,H,D,T] bf16
__global__ __launch_bounds__(256) void gemm_qkv_kernel(const ushort* __restrict__ A,
                                                       const ushort* __restrict__ W,
                                                       const float* __restrict__ bias,
                                                       ushort* __restrict__ qb,
                                                       ushort* __restrict__ kb,
                                                       ushort* __restrict__ vb) {
  const int K = 2048;
  __shared__ ushort lA[128 * 32];
  __shared__ ushort lB[128 * 32];
  const int tid = threadIdx.x;
  const int lane = tid & 63, wid = tid >> 6;
  const int wr = wid >> 1, wc = wid & 1;
  const int ar = lane & 15, ak = (lane >> 4) * 8;
  const int row0 = blockIdx.y * 128;
  const int col0 = blockIdx.x * 128;
  f32x4 acc[4][4];
#pragma unroll
  for (int m = 0; m < 4; ++m)
#pragma unroll
    for (int n = 0; n < 4; ++n) acc[m][n] = (f32x4){0.f, 0.f, 0.f, 0.f};
  for (int k0 = 0; k0 < K; k0 += 32) {
#pragma unroll
    for (int i = 0; i < 2; ++i) {
      int e = (i * 256 + tid) * 8;
      int r = e >> 5, c = e & 31;
      __builtin_amdgcn_global_load_lds((glb_u32_t*)(A + (size_t)(row0 + r) * K + k0 + c),
                                       (lds_u32_t*)(&lA[e]), 16, 0, 0);
      __builtin_amdgcn_global_load_lds((glb_u32_t*)(W + (size_t)(col0 + r) * K + k0 + c),
                                       (lds_u32_t*)(&lB[e]), 16, 0, 0);
    }
    __syncthreads();
    bf16x8 af[4], bfr[4];
#pragma unroll
    for (int m = 0; m < 4; ++m) af[m] = *(const bf16x8*)&lA[(wr * 64 + m * 16 + ar) * 32 + ak];
#pragma unroll
    for (int n = 0; n < 4; ++n) bfr[n] = *(const bf16x8*)&lB[(wc * 64 + n * 16 + ar) * 32 + ak];
#pragma unroll
    for (int m = 0; m < 4; ++m)
#pragma unroll
      for (int n = 0; n < 4; ++n)
        acc[m][n] = __builtin_amdgcn_mfma_f32_16x16x32_bf16(af[m], bfr[n], acc[m][n], 0, 0, 0);
    __syncthreads();
  }
  int s = col0 >> 11;
  int hh = (col0 >> 7) & 15;
  if (s < 2) {
    ushort* dst = (s == 0) ? qb : kb;
#pragma unroll
    for (int n = 0; n < 4; ++n) {
      int d = wc * 64 + n * 16 + ar;
      float bv = bias[col0 + d];
#pragma unroll
      for (int m = 0; m < 4; ++m) {
#pragma unroll
        for (int r = 0; r < 4; ++r) {
          int mrow = row0 + wr * 64 + m * 16 + (lane >> 4) * 4 + r;
          int bb = mrow >> 11, tt = mrow & 2047;
          dst[((size_t)(bb * 16 + hh) * 2048 + tt) * 128 + d] = f2bf(acc[m][n][r] + bv);
        }
      }
    }
  } else {
    // v transposed: vb[((b*16+h)*128 + d)*2048 + t]
#pragma unroll
    for (int n = 0; n < 4; ++n) {
      int d = wc * 64 + n * 16 + ar;
      float bv = bias[col0 + d];
#pragma unroll
      for (int m = 0; m < 4; ++m) {
        int t0 = row0 + wr * 64 + m * 16 + (lane >> 4) * 4;
        int bb = t0 >> 11, tt0 = t0 & 2047;
        ushort4 o;
        o.x = f2bf(acc[m][n][0] + bv);
        o.y = f2bf(acc[m][n][1] + bv);
        o.z = f2bf(acc[m][n][2] + bv);
        o.w = f2bf(acc[m][n][3] + bv);
        *(ushort4*)&vb[(((size_t)(bb * 16 + hh) * 128) + d) * 2048 + tt0] = o;
      }
    }
  }
}

// ---------------- RoPE in-place on q and k; fold 1/sqrt(D) into q ----------------
__global__ __launch_bounds__(256) void rope_apply_kernel(ushort* __restrict__ q,
                                                         ushort* __restrict__ k,
                                                         const float* __restrict__ cs,
                                                         const float* __restrict__ sn) {
  const float scale = 0.08838834764831845f;  // 1/sqrt(128)
  int row = blockIdx.x * 4 + (threadIdx.x >> 6);  // [B*H*T) rows
  int j = threadIdx.x & 63;
  int t = row & 2047;
  float c = cs[t * 64 + j], s = sn[t * 64 + j];
  size_t base = (size_t)row * 128;
  {
    float a = bf2f(q[base + j]), b = bf2f(q[base + 64 + j]);
    q[base + j] = f2bf((a * c - b * s) * scale);
    q[base + 64 + j] = f2bf((b * c + a * s) * scale);
  }
  {
    float a = bf2f(k[base + j]), b = bf2f(k[base + 64 + j]);
    k[base + j] = f2bf(a * c - b * s);
    k[base + 64 + j] = f2bf(b * c + a * s);
  }
}

// ---------------- causal flash attention (LDS-staged K/V, XOR-swizzled) ----------------
// 1D grid 1024 blocks; 4 waves/block; wave owns 16 q rows (QBLK=64/block, KVBLK=64)
// XCD swizzle: xcd = blk&7 -> bh group of 4 heads per XCD (K/V set = 4MB = L2)
__global__ __launch_bounds__(256) void attn_kernel(const ushort* __restrict__ Q,
                                                   const ushort* __restrict__ K,
                                                   const ushort* __restrict__ Vt,
                                                   ushort* __restrict__ O) {
  __shared__ ushort kT[64 * 128];   // K tile, rows 256B, XOR-swizzled
  __shared__ ushort vT[128 * 64];   // Vt tile, rows 128B, XOR-swizzled
  __shared__ ushort plds[4][16][72];
  const int tid = threadIdx.x;
  const int lane = tid & 63, wid = tid >> 6;
  const int ar = lane & 15, g = lane >> 4;  // g = lane group 0..3
  const int akk = g * 8;
  int blk = blockIdx.x;
  int xcd = blk & 7, j = blk >> 3;
  int bh = xcd * 4 + (j >> 5);
  int qt = 31 - (j & 31);  // long blocks first
  int b = bh >> 4, h = bh & 15;
  const ushort* Qb = Q + (size_t)bh * (2048 * 128);
  const ushort* Kb = K + (size_t)bh * (2048 * 128);
  const ushort* Vtb = Vt + (size_t)bh * (128 * 2048);
  int qrow0 = qt * 64 + wid * 16;
  bf16x8 qf[4];
#pragma unroll
  for (int kk = 0; kk < 4; ++kk)
    qf[kk] = *(const bf16x8*)&Qb[(size_t)(qrow0 + ar) * 128 + kk * 32 + akk];
  float m_r[4] = {-1e30f, -1e30f, -1e30f, -1e30f};
  float l_r[4] = {0.f, 0.f, 0.f, 0.f};
  f32x4 accO[8];
#pragma unroll
  for (int n = 0; n < 8; ++n) accO[n] = (f32x4){0.f, 0.f, 0.f, 0.f};
  int ntiles = qt + 1;
  for (int tt = 0; tt < ntiles; ++tt) {
    int kv0 = tt * 64;
    // ---- stage K (16KB) and V (16KB) into LDS, inverse-swizzled global source ----
#pragma unroll
    for (int i = 0; i < 4; ++i) {
      int e = (i * 256 + tid) * 16;  // byte offset
      {
        int r = e >> 8, bs = (e & 255) ^ ((r & 7) << 4);
        __builtin_amdgcn_global_load_lds(
            (glb_u32_t*)(Kb + (size_t)(kv0 + r) * 128 + (bs >> 1)),
            (lds_u32_t*)((char*)kT + e), 16, 0, 0);
      }
      {
        int r = e >> 7, bs = (e & 127) ^ ((r & 7) << 4);
        __builtin_amdgcn_global_load_lds(
            (glb_u32_t*)(Vtb + (size_t)r * 2048 + kv0 + (bs >> 1)),
            (lds_u32_t*)((char*)vT + e), 16, 0, 0);
      }
    }
    __syncthreads();  // drains vmcnt
    // ---- QK^T from LDS ----
    f32x4 s4[4];
#pragma unroll
    for (int n = 0; n < 4; ++n) {
      s4[n] = (f32x4){0.f, 0.f, 0.f, 0.f};
      int r = n * 16 + ar;
      int swz = (r & 7) << 4;
#pragma unroll
      for (int kk = 0; kk < 4; ++kk) {
        int byte = (kk * 64 + g * 16) ^ swz;
        bf16x8 kf = *(const bf16x8*)&kT[((r << 8) + byte) >> 1];
        s4[n] = __builtin_amdgcn_mfma_f32_16x16x32_bf16(qf[kk], kf, s4[n], 0, 0, 0);
      }
    }
    const bool masked = (tt == ntiles - 1);
    float corr[4];
#pragma unroll
    for (int r = 0; r < 4; ++r) {
      int row = qrow0 + g * 4 + r;
      float v[4];
#pragma unroll
      for (int n = 0; n < 4; ++n) {
        int c = kv0 + n * 16 + ar;
        v[n] = (masked && c > row) ? -1e30f : s4[n][r];
      }
      float mx = fmaxf(fmaxf(v[0], v[1]), fmaxf(v[2], v[3]));
#pragma unroll
      for (int off = 1; off < 16; off <<= 1) mx = fmaxf(mx, __shfl_xor(mx, off));
      float mn = fmaxf(m_r[r], mx);
      float p0 = __expf(v[0] - mn), p1 = __expf(v[1] - mn);
      float p2 = __expf(v[2] - mn), p3 = __expf(v[3] - mn);
      float rs = (p0 + p1) + (p2 + p3);
#pragma unroll
      for (int off = 1; off < 16; off <<= 1) rs += __shfl_xor(rs, off);
      corr[r] = __expf(m_r[r] - mn);
      l_r[r] = l_r[r] * corr[r] + rs;
      m_r[r] = mn;
      int qr = g * 4 + r;
      plds[wid][qr][ar] = f2bf(p0);
      plds[wid][qr][16 + ar] = f2bf(p1);
      plds[wid][qr][32 + ar] = f2bf(p2);
      plds[wid][qr][48 + ar] = f2bf(p3);
    }
#pragma unroll
    for (int n = 0; n < 8; ++n) {
#pragma unroll
      for (int r = 0; r < 4; ++r) accO[n][r] *= corr[r];
    }
    asm volatile("s_waitcnt lgkmcnt(0)" ::: "memory");
    bf16x8 pf0 = *(const bf16x8*)&plds[wid][ar][akk];
    bf16x8 pf1 = *(const bf16x8*)&plds[wid][ar][32 + akk];
    // ---- PV from LDS V tile ----
#pragma unroll
    for (int n = 0; n < 8; ++n) {
      int r = n * 16 + ar;
      int swz = (r & 7) << 4;
      bf16x8 vf0 = *(const bf16x8*)&vT[((r << 7) + ((g * 16) ^ swz)) >> 1];
      accO[n] = __builtin_amdgcn_mfma_f32_16x16x32_bf16(pf0, vf0, accO[n], 0, 0, 0);
      bf16x8 vf1 = *(const bf16x8*)&vT[((r << 7) + ((64 + g * 16) ^ swz)) >> 1];
      accO[n] = __builtin_amdgcn_mfma_f32_16x16x32_bf16(pf1, vf1, accO[n], 0, 0, 0);
    }
    __syncthreads();  // protect K/V LDS before next stage
  }
  // write O to [B,T,H*D] (bf16) for the O-proj GEMM
#pragma unroll
  for (int r = 0; r < 4; ++r) {
    int trow = qrow0 + g * 4 + r;
    float invl = 1.0f / l_r[r];
    ushort* orow = O + ((size_t)b * 2048 + trow) * 2048 + h * 128;
#pragma unroll
    for (int n = 0; n < 8; ++n) orow[n * 16 + ar] = f2bf(accO[n][r] * invl);
  }
}

// ---------------- O-proj GEMM: [4096,2048] x [2048,2048]^T + bias -> fp32 out ----------------
__global__ __launch_bounds__(256) void gemm_oproj_kernel(const ushort* __restrict__ A,
                                                         const ushort* __restrict__ W,
                                                         const float* __restrict__ bias,
                                                         float* __restrict__ out) {
  const int K = 2048;
  __shared__ ushort lA[128 * 32];
  __shared__ ushort lB[128 * 32];
  const int tid = threadIdx.x;
  const int lane = tid & 63, wid = tid >> 6;
  const int wr = wid >> 1, wc = wid & 1;
  const int ar = lane & 15, ak = (lane >> 4) * 8;
  const int row0 = blockIdx.y * 128;
  const int col0 = blockIdx.x * 128;
  f32x4 acc[4][4];
#pragma unroll
  for (int m = 0; m < 4; ++m)
#pragma unroll
    for (int n = 0; n < 4; ++n) acc[m][n] = (f32x4){0.f, 0.f, 0.f, 0.f};
  for (int k0 = 0; k0 < K; k0 += 32) {
#pragma unroll
    for (int i = 0; i < 2; ++i) {
      int e = (i * 256 + tid) * 8;
      int r = e >> 5, c = e & 31;
      __builtin_amdgcn_global_load_lds((glb_u32_t*)(A + (size_t)(row0 + r) * K + k0 + c),
                                       (lds_u32_t*)(&lA[e]), 16, 0, 0);
      __builtin_amdgcn_global_load_lds((glb_u32_t*)(W + (size_t)(col0 + r) * K + k0 + c),
                                       (lds_u32_t*)(&lB[e]), 16, 0, 0);
    }
    __syncthreads();
    bf16x8 af[4], bfr[4];
#pragma unroll
    for (int m = 0; m < 4; ++m) af[m] = *(const bf16x8*)&lA[(wr * 64 + m * 16 + ar) * 32 + ak];
#pragma unroll
    for (int n = 0; n < 4; ++n) bfr[n] = *(const bf16x8*)&lB[(wc * 64 + n * 16 + ar) * 32 + ak];
#pragma unroll
    for (int m = 0; m < 4; ++m)
#pragma unroll
      for (int n = 0; n < 4; ++n)
        acc[m][n] = __builtin_amdgcn_mfma_f32_16x16x32_bf16(af[m], bfr[n], acc[m][n], 0, 0, 0);
    __syncthreads();
  }
#pragma unroll
  for (int n = 0; n < 4; ++n) {
    int col = col0 + wc * 64 + n * 16 + ar;
    float bv = bias[col];
#pragma unroll
    for (int m = 0; m < 4; ++m) {
#pragma unroll
      for (int r = 0; r < 4; ++r) {
        int mrow = row0 + wr * 64 + m * 16 + (lane >> 4) * 4 + r;
        out[(size_t)mrow * 2048 + col] = acc[m][n][r] + bv;
      }
    }
  }
}

extern "C" void kernel_launch(void* const* d_in, const int* in_sizes, int n_in,
                              void* d_out, int out_size, void* d_ws, size_t ws_size,
                              hipStream_t stream) {
  const float* x = (const float*)d_in[0];
  const float* rmsw = (const float*)d_in[1];
  const float* qkv_w = (const float*)d_in[2];
  const float* qkv_b = (const float*)d_in[3];
  const float* o_w = (const float*)d_in[4];
  const float* o_b = (const float*)d_in[5];
  float* out = (float*)d_out;

  char* ws = (char*)d_ws;
  size_t off = 0;
  auto alloc = [&](size_t bytes) {
    void* p = ws + off;
    off += (bytes + 255) & ~(size_t)255;
    return p;
  };
  ushort* xn = (ushort*)alloc((size_t)4096 * 2048 * 2);  // later reused as attn_out
  ushort* wq = (ushort*)alloc((size_t)6144 * 2048 * 2);
  ushort* wo = (ushort*)alloc((size_t)2048 * 2048 * 2);
  ushort* qb = (ushort*)alloc((size_t)32 * 2048 * 128 * 2);
  ushort* kb = (ushort*)alloc((size_t)32 * 2048 * 128 * 2);
  ushort* vb = (ushort*)alloc((size_t)32 * 2048 * 128 * 2);  // [B,H,D,T]
  float* cs = (float*)alloc((size_t)2048 * 64 * 4);
  float* sn = (float*)alloc((size_t)2048 * 64 * 4);

  cast_f32_to_bf16<<<1024, 256, 0, stream>>>(qkv_w, wq, 6144 * 2048 / 4);
  cast_f32_to_bf16<<<1024, 256, 0, stream>>>(o_w, wo, 2048 * 2048 / 4);
  rope_table_kernel<<<512, 256, 0, stream>>>(cs, sn);
  rmsnorm_kernel<<<4096, 256, 0, stream>>>(x, rmsw, xn);
  gemm_qkv_kernel<<<dim3(48, 32), 256, 0, stream>>>(xn, wq, qkv_b, qb, kb, vb);
  rope_apply_kernel<<<16384, 256, 0, stream>>>(qb, kb, cs, sn);
  attn_kernel<<<1024, 256, 0, stream>>>(qb, kb, vb, xn /* attn_out */);
  gemm_oproj_kernel<<<dim3(16, 32), 256, 0, stream>>>(xn, wo, o_b, out);
}